// Round 2
// baseline (54.351 us; speedup 1.0000x reference)
//
#include <hip/hip_runtime.h>
#include <stdint.h>

#define N_GATES   16384
#define NUM_IN    256
#define NUM_OUT   256
#define MID_LAYERS 15
#define W         4096
#define BLOCK     1024
#define WG_COLS   32               // bit-columns handled per workgroup
#define NUM_WG    (W / WG_COLS)    // 128

// One workgroup owns bit-columns [32*wg, 32*wg+32). The whole layer slice
// (16384 gates x 32 bits = 64KB) lives in LDS, double-buffered (128KB),
// plus 1KB for the packed input/output words. All 17 layers run inside the
// workgroup with only __syncthreads() between layers.
__global__ __launch_bounds__(BLOCK)
void nand_graph_kernel(const uint32_t* __restrict__ input_bits, // 256*4096 int32 0/1
                       const int2*     __restrict__ idx0,       // 16384 pairs in [0,256)
                       const int2*     __restrict__ idx_mid,    // 15*16384 pairs in [0,16384)
                       const int2*     __restrict__ idx_out,    // 256 pairs in [0,16384)
                       const uint32_t* __restrict__ nor0,       // 16384 flags
                       const uint32_t* __restrict__ nor_mid,    // 15*16384 flags
                       const uint32_t* __restrict__ nor_out,    // 256 flags
                       int*            __restrict__ out)        // 256*4096 int32 0/1
{
    extern __shared__ uint32_t lds[];
    uint32_t* bufA = lds;                 // 16384 words
    uint32_t* bufB = lds + N_GATES;       // 16384 words
    uint32_t* wrd  = lds + 2 * N_GATES;   // 256 words (input pack, later output pack)

    const int wg   = blockIdx.x;          // 0..127
    const int tid  = threadIdx.x;         // 0..1023
    const int lane = tid & 63;
    const int wave = tid >> 6;            // 0..15
    const int colbase = wg * WG_COLS;

    // ---- pack input_bits columns [colbase, colbase+32) into wrd[256] ----
    // Each wave packs 2 rows per iteration via ballot: lanes 0-31 -> row r2*2,
    // lanes 32-63 -> row r2*2+1; ballot bit l corresponds to column (l&31).
    for (int r2 = wave; r2 < NUM_IN / 2; r2 += BLOCK / 64) {
        int r = r2 * 2 + (lane >> 5);
        int c = lane & 31;
        uint32_t v = input_bits[r * W + colbase + c];
        unsigned long long m = __ballot(v != 0u);
        if ((lane & 31) == 0) {
            wrd[r] = (uint32_t)(m >> ((lane >> 5) * 32));
        }
    }
    __syncthreads();

    // ---- layer 0: gates read the 256 packed input words ----
    for (int g = tid; g < N_GATES; g += BLOCK) {
        int2 ix = idx0[g];
        uint32_t a = wrd[ix.x];
        uint32_t b = wrd[ix.y];
        uint32_t nn = nor0[g];
        bufA[g] = ~(nn ? (a | b) : (a & b));
    }
    __syncthreads();

    // ---- 15 mid layers, LDS ping-pong ----
    uint32_t* cur = bufA;
    uint32_t* nxt = bufB;
    for (int l = 0; l < MID_LAYERS; ++l) {
        const int2*     idx = idx_mid + (size_t)l * N_GATES;
        const uint32_t* nor = nor_mid + (size_t)l * N_GATES;
        for (int g = tid; g < N_GATES; g += BLOCK) {
            int2 ix = idx[g];
            uint32_t a = cur[ix.x];
            uint32_t b = cur[ix.y];
            uint32_t nn = nor[g];
            nxt[g] = ~(nn ? (a | b) : (a & b));
        }
        __syncthreads();
        uint32_t* t = cur; cur = nxt; nxt = t;
    }

    // ---- output layer: 256 gates -> wrd[256] (input words no longer needed) ----
    if (tid < NUM_OUT) {
        int2 ix = idx_out[tid];
        uint32_t a = cur[ix.x];
        uint32_t b = cur[ix.y];
        uint32_t nn = nor_out[tid];
        wrd[tid] = ~(nn ? (a | b) : (a & b));
    }
    __syncthreads();

    // ---- unpack: write 256 rows x 32 columns of int 0/1 ----
    for (int r2 = wave; r2 < NUM_OUT / 2; r2 += BLOCK / 64) {
        int r = r2 * 2 + (lane >> 5);
        int c = lane & 31;
        uint32_t bits = wrd[r];
        out[r * W + colbase + c] = (int)((bits >> c) & 1u);
    }
}

extern "C" void kernel_launch(void* const* d_in, const int* in_sizes, int n_in,
                              void* d_out, int out_size, void* d_ws, size_t ws_size,
                              hipStream_t stream) {
    const uint32_t* input_bits = (const uint32_t*)d_in[0];
    const int2*     idx0       = (const int2*)d_in[1];
    const int2*     idx_mid    = (const int2*)d_in[2];
    const int2*     idx_out    = (const int2*)d_in[3];
    const uint32_t* nor0       = (const uint32_t*)d_in[4];
    const uint32_t* nor_mid    = (const uint32_t*)d_in[5];
    const uint32_t* nor_out    = (const uint32_t*)d_in[6];
    int*            out        = (int*)d_out;

    const size_t lds_bytes = (size_t)(2 * N_GATES + 256) * sizeof(uint32_t); // 132096 B

    // Opt in to >64KB dynamic LDS (deterministic, not a stream op — capture-safe).
    hipFuncSetAttribute(reinterpret_cast<const void*>(nand_graph_kernel),
                        hipFuncAttributeMaxDynamicSharedMemorySize, (int)lds_bytes);

    nand_graph_kernel<<<dim3(NUM_WG), dim3(BLOCK), lds_bytes, stream>>>(
        input_bits, idx0, idx_mid, idx_out, nor0, nor_mid, nor_out, out);
}

// Round 3
// 47.950 us; speedup vs baseline: 1.1335x; 1.1335x over previous
//
#include <hip/hip_runtime.h>
#include <stdint.h>

#define N_GATES   16384
#define NUM_IN    256
#define NUM_OUT   256
#define MID_LAYERS 15
#define W         4096
#define BLOCK     1024
#define WG_COLS   32               // bit-columns handled per workgroup
#define NUM_WG    (W / WG_COLS)    // 128
#define PAIRS_PER_THREAD (N_GATES / (2 * BLOCK))   // 8

// One workgroup owns bit-columns [32*wg, 32*wg+32). The whole layer slice
// (16384 gates x 32 bits = 64KB) lives in LDS, double-buffered (128KB),
// plus 1KB of packed input/output words. All 17 layers run inside the
// workgroup with one __syncthreads() per layer.
//
// DS-pipe cost model (per CU per layer): 512 random-gather ds_read_b32
// (~10.8 cyc incl. conflicts, inherent to random operands) + 128 paired
// ds_write_b64 (conflict-free, lanes at 8B stride). idx/nor loads are
// hoisted to registers at layer start so global latency doesn't stall
// the DS pipe mid-layer.
__global__ __launch_bounds__(BLOCK, 4)
void nand_graph_kernel(const uint32_t* __restrict__ input_bits, // 256*4096 int32 0/1
                       const int4*     __restrict__ idx0_v,     // 16384 pairs, viewed as int4 (2 gates)
                       const int4*     __restrict__ idx_mid_v,  // 15*16384 pairs as int4
                       const int2*     __restrict__ idx_out,    // 256 pairs in [0,16384)
                       const int2*     __restrict__ nor0_v,     // 16384 flags as int2 (2 gates)
                       const int2*     __restrict__ nor_mid_v,  // 15*16384 flags as int2
                       const uint32_t* __restrict__ nor_out,    // 256 flags
                       int*            __restrict__ out)        // 256*4096 int32 0/1
{
    extern __shared__ uint32_t lds[];
    uint32_t* bufA = lds;                 // 16384 words
    uint32_t* bufB = lds + N_GATES;       // 16384 words
    uint32_t* wrd  = lds + 2 * N_GATES;   // 256 words (input pack, later output pack)

    const int wg   = blockIdx.x;          // 0..127
    const int tid  = threadIdx.x;         // 0..1023
    const int lane = tid & 63;
    const int wave = tid >> 6;            // 0..15
    const int colbase = wg * WG_COLS;

    // ---- pack input_bits columns [colbase, colbase+32) into wrd[256] ----
    for (int r2 = wave; r2 < NUM_IN / 2; r2 += BLOCK / 64) {
        int r = r2 * 2 + (lane >> 5);
        int c = lane & 31;
        uint32_t v = input_bits[r * W + colbase + c];
        unsigned long long m = __ballot(v != 0u);
        if ((lane & 31) == 0) {
            wrd[r] = (uint32_t)(m >> ((lane >> 5) * 32));
        }
    }
    __syncthreads();

    // ---- layer 0: gates read the 256 packed input words ----
    {
        int4 ix[PAIRS_PER_THREAD];
        int2 nn[PAIRS_PER_THREAD];
        #pragma unroll
        for (int p = 0; p < PAIRS_PER_THREAD; ++p) {
            int P = tid + p * BLOCK;          // pair index; gates 2P, 2P+1
            ix[p] = idx0_v[P];
            nn[p] = nor0_v[P];
        }
        #pragma unroll
        for (int p = 0; p < PAIRS_PER_THREAD; ++p) {
            int P = tid + p * BLOCK;
            uint32_t a0 = wrd[ix[p].x], b0 = wrd[ix[p].y];
            uint32_t a1 = wrd[ix[p].z], b1 = wrd[ix[p].w];
            uint32_t r0 = ~(nn[p].x ? (a0 | b0) : (a0 & b0));
            uint32_t r1 = ~(nn[p].y ? (a1 | b1) : (a1 & b1));
            // paired conflict-free write: lanes at 8B stride
            *reinterpret_cast<uint2*>(&bufA[2 * P]) = make_uint2(r0, r1);
        }
    }
    __syncthreads();

    // ---- 15 mid layers, LDS ping-pong ----
    uint32_t* cur = bufA;
    uint32_t* nxt = bufB;
    for (int l = 0; l < MID_LAYERS; ++l) {
        const int4* idxv = idx_mid_v + (size_t)l * (N_GATES / 2);
        const int2* norv = nor_mid_v + (size_t)l * (N_GATES / 2);

        // hoist all of this thread's gate descriptors into registers first
        int4 ix[PAIRS_PER_THREAD];
        int2 nn[PAIRS_PER_THREAD];
        #pragma unroll
        for (int p = 0; p < PAIRS_PER_THREAD; ++p) {
            int P = tid + p * BLOCK;
            ix[p] = idxv[P];
            nn[p] = norv[P];
        }
        #pragma unroll
        for (int p = 0; p < PAIRS_PER_THREAD; ++p) {
            int P = tid + p * BLOCK;
            uint32_t a0 = cur[ix[p].x], b0 = cur[ix[p].y];
            uint32_t a1 = cur[ix[p].z], b1 = cur[ix[p].w];
            uint32_t r0 = ~(nn[p].x ? (a0 | b0) : (a0 & b0));
            uint32_t r1 = ~(nn[p].y ? (a1 | b1) : (a1 & b1));
            *reinterpret_cast<uint2*>(&nxt[2 * P]) = make_uint2(r0, r1);
        }
        __syncthreads();
        uint32_t* t = cur; cur = nxt; nxt = t;
    }

    // ---- output layer: 256 gates -> wrd[256] ----
    if (tid < NUM_OUT) {
        int2 ix = idx_out[tid];
        uint32_t a = cur[ix.x];
        uint32_t b = cur[ix.y];
        uint32_t nn = nor_out[tid];
        wrd[tid] = ~(nn ? (a | b) : (a & b));
    }
    __syncthreads();

    // ---- unpack: write 256 rows x 32 columns of int 0/1 ----
    for (int r2 = wave; r2 < NUM_OUT / 2; r2 += BLOCK / 64) {
        int r = r2 * 2 + (lane >> 5);
        int c = lane & 31;
        uint32_t bits = wrd[r];
        out[r * W + colbase + c] = (int)((bits >> c) & 1u);
    }
}

extern "C" void kernel_launch(void* const* d_in, const int* in_sizes, int n_in,
                              void* d_out, int out_size, void* d_ws, size_t ws_size,
                              hipStream_t stream) {
    const uint32_t* input_bits = (const uint32_t*)d_in[0];
    const int4*     idx0_v     = (const int4*)d_in[1];
    const int4*     idx_mid_v  = (const int4*)d_in[2];
    const int2*     idx_out    = (const int2*)d_in[3];
    const int2*     nor0_v     = (const int2*)d_in[4];
    const int2*     nor_mid_v  = (const int2*)d_in[5];
    const uint32_t* nor_out    = (const uint32_t*)d_in[6];
    int*            out        = (int*)d_out;

    const size_t lds_bytes = (size_t)(2 * N_GATES + 256) * sizeof(uint32_t); // 132096 B

    hipFuncSetAttribute(reinterpret_cast<const void*>(nand_graph_kernel),
                        hipFuncAttributeMaxDynamicSharedMemorySize, (int)lds_bytes);

    nand_graph_kernel<<<dim3(NUM_WG), dim3(BLOCK), lds_bytes, stream>>>(
        input_bits, idx0_v, idx_mid_v, idx_out, nor0_v, nor_mid_v, nor_out, out);
}

// Round 4
// 43.731 us; speedup vs baseline: 1.2429x; 1.0965x over previous
//
#include <hip/hip_runtime.h>
#include <stdint.h>

#define N_GATES    16384
#define NUM_IN     256
#define NUM_OUT    256
#define MID_LAYERS 15
#define W          4096
#define BLOCK      1024
#define WG_COLS    16              // bit-columns per workgroup (uint16 words)
#define NUM_WG     (W / WG_COLS)   // 256 -> one WG per CU on all 256 CUs
#define QPT        (N_GATES / (4 * BLOCK))  // 4 quads (of 4 gates) per thread

// One workgroup owns 16 bit-columns as uint16 words. Full layer slice =
// 16384 x 2B = 32KB, double-buffered (64KB) + 512B packed I/O words.
// All 17 layers run in-workgroup, one __syncthreads() per layer.
//
// DS cost model (per CU per layer): 512 random-gather ds_read_u16 (128B/wave,
// conflicts inherent to random operands) + 64 ds_write_b64 (4 gates packed,
// conflict-free). Descriptor int4-loads for layer l+1 are issued BEFORE the
// barrier that ends layer l, hiding L2 latency under the gathers.
__global__ __launch_bounds__(BLOCK, 2)
void nand_graph_kernel(const uint32_t* __restrict__ input_bits, // 256*4096 int 0/1
                       const int4*     __restrict__ idx0_4,     // 16384 pairs as 8192 int4
                       const int4*     __restrict__ idx_mid_4,  // 15*8192 int4
                       const int2*     __restrict__ idx_out,    // 256 pairs
                       const int4*     __restrict__ nor0_4,     // 16384 flags as 4096 int4
                       const int4*     __restrict__ nor_mid_4,  // 15*4096 int4
                       const uint32_t* __restrict__ nor_out,    // 256 flags
                       int*            __restrict__ out)        // 256*4096 int 0/1
{
    extern __shared__ __align__(16) uint16_t lds16[];
    uint16_t* bufA = lds16;                 // 16384 u16
    uint16_t* bufB = lds16 + N_GATES;       // 16384 u16
    uint16_t* wrd  = lds16 + 2 * N_GATES;   // 256 u16 (input pack / output pack)

    const int tid     = threadIdx.x;        // 0..1023
    const int lane    = tid & 63;
    const int wave    = tid >> 6;           // 0..15
    const int colbase = blockIdx.x * WG_COLS;

    int4 ixA[QPT], ixB[QPT], nnq[QPT];      // descriptors for the layer being (or about to be) run

    // ---- issue layer-0 descriptor loads early (hide under input pack) ----
    #pragma unroll
    for (int q = 0; q < QPT; ++q) {
        int Q = tid + q * BLOCK;            // quad index; gates 4Q..4Q+3
        ixA[q] = idx0_4[2 * Q];
        ixB[q] = idx0_4[2 * Q + 1];
        nnq[q] = nor0_4[Q];
    }

    // ---- pack input_bits columns [colbase, colbase+16) into wrd[256] ----
    // Each wave handles 4 rows per iteration via ballot: lane group g=(lane>>4)
    // covers row it*4+g, ballot bit l -> column (l&15).
    #pragma unroll
    for (int it = wave; it < NUM_IN / 4; it += BLOCK / 64) {
        int r = it * 4 + (lane >> 4);
        int c = lane & 15;
        uint32_t v = input_bits[r * W + colbase + c];
        unsigned long long m = __ballot(v != 0u);
        if ((lane & 15) == 0)
            wrd[r] = (uint16_t)(m >> ((lane >> 4) * 16));
    }
    __syncthreads();

    auto run_gates = [&](const uint16_t* __restrict__ src, uint16_t* __restrict__ dst) {
        #pragma unroll
        for (int q = 0; q < QPT; ++q) {
            int Q = tid + q * BLOCK;
            uint32_t a0 = src[ixA[q].x], b0 = src[ixA[q].y];
            uint32_t a1 = src[ixA[q].z], b1 = src[ixA[q].w];
            uint32_t a2 = src[ixB[q].x], b2 = src[ixB[q].y];
            uint32_t a3 = src[ixB[q].z], b3 = src[ixB[q].w];
            uint32_t r0 = ~(nnq[q].x ? (a0 | b0) : (a0 & b0));
            uint32_t r1 = ~(nnq[q].y ? (a1 | b1) : (a1 & b1));
            uint32_t r2 = ~(nnq[q].z ? (a2 | b2) : (a2 & b2));
            uint32_t r3 = ~(nnq[q].w ? (a3 | b3) : (a3 & b3));
            uint32_t lo = (r0 & 0xFFFFu) | (r1 << 16);
            uint32_t hi = (r2 & 0xFFFFu) | (r3 << 16);
            // 4 gates packed -> one conflict-free ds_write_b64 (8B lane stride)
            *reinterpret_cast<uint2*>(dst + 4 * Q) = make_uint2(lo, hi);
        }
    };

    // ---- layer 0: gates read the 256 packed input words ----
    run_gates(wrd, bufA);
    // prefetch mid-layer 0 descriptors before the barrier
    {
        const int4* i4 = idx_mid_4;
        const int4* n4 = nor_mid_4;
        #pragma unroll
        for (int q = 0; q < QPT; ++q) {
            int Q = tid + q * BLOCK;
            ixA[q] = i4[2 * Q];
            ixB[q] = i4[2 * Q + 1];
            nnq[q] = n4[Q];
        }
    }
    __syncthreads();

    // ---- 15 mid layers, LDS ping-pong, descriptor prefetch across barrier ----
    uint16_t* cur = bufA;
    uint16_t* nxt = bufB;
    for (int l = 0; l < MID_LAYERS; ++l) {
        run_gates(cur, nxt);
        if (l + 1 < MID_LAYERS) {
            const int4* i4 = idx_mid_4 + (size_t)(l + 1) * (N_GATES / 2);
            const int4* n4 = nor_mid_4 + (size_t)(l + 1) * (N_GATES / 4);
            #pragma unroll
            for (int q = 0; q < QPT; ++q) {
                int Q = tid + q * BLOCK;
                ixA[q] = i4[2 * Q];
                ixB[q] = i4[2 * Q + 1];
                nnq[q] = n4[Q];
            }
        }
        __syncthreads();
        uint16_t* t = cur; cur = nxt; nxt = t;
    }

    // ---- output layer: 256 gates -> wrd[256] ----
    if (tid < NUM_OUT) {
        int2 ix = idx_out[tid];
        uint32_t a = cur[ix.x];
        uint32_t b = cur[ix.y];
        wrd[tid] = (uint16_t)~(nor_out[tid] ? (a | b) : (a & b));
    }
    __syncthreads();

    // ---- unpack: 256 rows x 16 columns of int 0/1 ----
    #pragma unroll
    for (int i = tid; i < NUM_OUT * WG_COLS; i += BLOCK) {
        int r = i >> 4, c = i & 15;
        out[r * W + colbase + c] = (int)((wrd[r] >> c) & 1u);
    }
}

extern "C" void kernel_launch(void* const* d_in, const int* in_sizes, int n_in,
                              void* d_out, int out_size, void* d_ws, size_t ws_size,
                              hipStream_t stream) {
    const uint32_t* input_bits = (const uint32_t*)d_in[0];
    const int4*     idx0_4     = (const int4*)d_in[1];
    const int4*     idx_mid_4  = (const int4*)d_in[2];
    const int2*     idx_out    = (const int2*)d_in[3];
    const int4*     nor0_4     = (const int4*)d_in[4];
    const int4*     nor_mid_4  = (const int4*)d_in[5];
    const uint32_t* nor_out    = (const uint32_t*)d_in[6];
    int*            out        = (int*)d_out;

    const size_t lds_bytes = (size_t)(2 * N_GATES + 256) * sizeof(uint16_t); // 66048 B

    hipFuncSetAttribute(reinterpret_cast<const void*>(nand_graph_kernel),
                        hipFuncAttributeMaxDynamicSharedMemorySize, (int)lds_bytes);

    nand_graph_kernel<<<dim3(NUM_WG), dim3(BLOCK), lds_bytes, stream>>>(
        input_bits, idx0_4, idx_mid_4, idx_out, nor0_4, nor_mid_4, nor_out, out);
}